// Round 2
// baseline (2676.978 us; speedup 1.0000x reference)
//
#include <hip/hip_runtime.h>

// ---------------------------------------------------------------------------
// MattingSolver CG on MI355X — round 12: R10 gather structure + split-row
// concurrency.
//
// R11 (scatter-inverted pull lists) REGRESSED 1879->2222: random-store +
// extra-stream cost in k_it1 exceeded k_it2's streaming gain. Reverted.
// R12 theory: iterations are latency-bound, not BW-bound (p/Lv/u_all are
// L2-resident; HBM math says ~12us/iter but we run ~55us). k_it2 has only
// 2.25 waves/SIMD (N threads), k_it1 CSR ~4.5 — too few to hide the
// dependent gather chains (gU->u_all, csrPk->p).
// R12: keep R10's proven kernels, but
//  * k_it2: 4 threads per row (grid 4N/TPB), stride-4 segment walk,
//    __shfl_xor combine -> 9 waves/SIMD; quad-lane index loads are 16B
//    contiguous.
//  * k_it1 CSR phase: 2 threads per row (CSR portion 2N/TPB blocks),
//    stride-2 walk, shfl combine -> ~6.75 waves/SIMD.
// Setup (k_hist atomic wall 158us) untouched. ws layout identical to R10.
// ---------------------------------------------------------------------------

#define TPB 256

__device__ __forceinline__ float blockReduce256(float v) {
  #pragma unroll
  for (int o = 32; o > 0; o >>= 1) v += __shfl_down(v, o, 64);
  __shared__ float s[4];
  int lane = threadIdx.x & 63, wv = threadIdx.x >> 6;
  if (lane == 0) s[wv] = v;
  __syncthreads();
  return (threadIdx.x == 0) ? (s[0] + s[1] + s[2] + s[3]) : 0.f;
}

// vectors, diag, b, scal, CNT zero, b.b  (grid: 3*Bn)
__global__ void k_init0(const float* __restrict__ KUw, const float* __restrict__ kToUconf,
                        const float* __restrict__ lmbda, const float* __restrict__ known,
                        const float* __restrict__ kToU,
                        float* __restrict__ diag_ku, float* __restrict__ r,
                        float* __restrict__ p, float* __restrict__ x,
                        int* __restrict__ CNT, float* __restrict__ scal, int N)
{
  int i = blockIdx.x * TPB + threadIdx.x;
  if (i < 80) scal[i] = 0.f;
  if (i < 3 * N) CNT[i] = 0;
  float red = 0.f;
  if (i < N) {
    float dk = KUw[i] * kToUconf[i] + lmbda[0] * known[i];
    diag_ku[i] = dk;
    float b = dk * kToU[i];
    r[i] = b; p[i] = b; x[i] = 0.f;
    red = b * b;
  }
  float v = blockReduce256(red);
  if (threadIdx.x == 0) atomicAdd(&scal[0], v);
}

// in-place symmetrization: LOC_flows rows 0..35 <- 0.5*w*(F_ab+F_ba), a<b.
// Thread k owns column k; harness restores d_in before every launch.
__global__ void k_prep(float* __restrict__ LOC_flows, const int* __restrict__ LOC_inInd,
                       const float* __restrict__ LOCw, int NLOC)
{
  int k = blockIdx.x * TPB + threadIdx.x;
  float Fl[81];
  #pragma unroll
  for (int m = 0; m < 81; ++m) Fl[m] = LOC_flows[(size_t)m * NLOC + k];
  float hw = 0.5f * LOCw[LOC_inInd[k]];
  int idx = 0;
  #pragma unroll
  for (int a = 0; a < 9; ++a)
    #pragma unroll
    for (int b = a + 1; b < 9; ++b) {
      LOC_flows[(size_t)idx * NLOC + k] = hw * (Fl[a * 9 + b] + Fl[b * 9 + a]);
      ++idx;
    }
}

// histograms + tickets  (grid: Bz + Bl + Bl)
__global__ void k_hist(const int* __restrict__ Wrow, const int* __restrict__ Wcol,
                       const int* __restrict__ LOC_inInd, const int* __restrict__ width_p,
                       const int* __restrict__ IU_inInd, const int* __restrict__ IU_neighInd,
                       int* __restrict__ CNT,
                       unsigned short* __restrict__ tr, unsigned short* __restrict__ tc,
                       unsigned short* __restrict__ tU,
                       int NLOC, int N, int B0, int B1)
{
  int blk = blockIdx.x;
  if (blk < B0) {
    int e = blk * TPB + threadIdx.x;
    tr[e] = (unsigned short)atomicAdd(&CNT[Wrow[e]], 1);
    tc[e] = (unsigned short)atomicAdd(&CNT[N + Wcol[e]], 1);
  } else if (blk < B1) {                // Wm: (k,a) by out-row
    int k = (blk - B0) * TPB + threadIdx.x;
    int wd = *width_p;
    int base = LOC_inInd[k];
    const int offs[9] = {-1 - wd, -1, -1 + wd, -wd, 0, wd, 1 - wd, 1, 1 + wd};
    #pragma unroll
    for (int a = 0; a < 9; ++a)
      tU[a * NLOC + k] = (unsigned short)atomicAdd(&CNT[2 * N + base + offs[a]], 1);
  } else {                              // Wc: dirA k by r0, dirB (k,j) by c0
    int k = (blk - B1) * TPB + threadIdx.x;
    tU[14 * NLOC + k] = (unsigned short)atomicAdd(&CNT[2 * N + IU_inInd[k]], 1);
    #pragma unroll
    for (int j = 0; j < 5; ++j)
      tU[(9 + j) * NLOC + k] =
          (unsigned short)atomicAdd(&CNT[2 * N + IU_neighInd[k * 5 + j]], 1);
  }
}

// in-place exclusive scan (OFF==CNT)
__global__ void k_scan1(int* __restrict__ OFF, int* __restrict__ bsum, int tot)
{
  __shared__ int s[TPB];
  int gid = blockIdx.x * TPB + threadIdx.x;
  int v = (gid < tot) ? OFF[gid] : 0;
  s[threadIdx.x] = v;
  __syncthreads();
  #pragma unroll
  for (int o = 1; o < TPB; o <<= 1) {
    int t = (threadIdx.x >= o) ? s[threadIdx.x - o] : 0;
    __syncthreads();
    s[threadIdx.x] += t;
    __syncthreads();
  }
  if (gid < tot) OFF[gid] = s[threadIdx.x] - v;
  if (threadIdx.x == TPB - 1) bsum[blockIdx.x] = s[threadIdx.x];
}

__global__ void k_scan2(int* __restrict__ bsum, int nPerArr)  // 3 blocks x 1024
{
  __shared__ int s[1024];
  int base = blockIdx.x * nPerArr;
  int v = (threadIdx.x < nPerArr) ? bsum[base + threadIdx.x] : 0;
  s[threadIdx.x] = v;
  __syncthreads();
  for (int o = 1; o < 1024; o <<= 1) {
    int t = (threadIdx.x >= o) ? s[threadIdx.x - o] : 0;
    __syncthreads();
    s[threadIdx.x] += t;
    __syncthreads();
  }
  if (threadIdx.x < nPerArr) bsum[base + threadIdx.x] = s[threadIdx.x] - v;
}

__global__ void k_scan3(int* __restrict__ OFF, const int* __restrict__ bsum, int tot)
{
  int gid = blockIdx.x * TPB + threadIdx.x;
  if (gid < tot) OFF[gid] += bsum[blockIdx.x];
}

// atomic-free fill: pos = OFF[key] + ticket  (grid: Bz + Bl + Bl)
__global__ void k_fill(const float* __restrict__ CMw, const float* __restrict__ Wcm_data,
                       const int* __restrict__ Wrow, const int* __restrict__ Wcol,
                       const int* __restrict__ LOC_inInd, const int* __restrict__ width_p,
                       const int* __restrict__ IU_inInd, const int* __restrict__ IU_neighInd,
                       const int* __restrict__ OFF,
                       const unsigned short* __restrict__ tr, const unsigned short* __restrict__ tc,
                       const unsigned short* __restrict__ tU,
                       int2* __restrict__ csrPk, int2* __restrict__ cscPk,
                       int* __restrict__ gU,
                       int NLOC, int N, int B0, int B1)
{
  int blk = blockIdx.x;
  if (blk < B0) {
    int e = blk * TPB + threadIdx.x;
    int row = Wrow[e], col = Wcol[e];
    int cv = __float_as_int(CMw[row] * Wcm_data[e]);
    csrPk[OFF[row] + tr[e]] = make_int2(col, cv);
    cscPk[OFF[N + col] + tc[e]] = make_int2(row, cv);
  } else if (blk < B1) {
    int k = (blk - B0) * TPB + threadIdx.x;
    int wd = *width_p;
    int base = LOC_inInd[k];
    const int offs[9] = {-1 - wd, -1, -1 + wd, -wd, 0, wd, 1 - wd, 1, 1 + wd};
    #pragma unroll
    for (int a = 0; a < 9; ++a)
      gU[OFF[2 * N + base + offs[a]] + tU[a * NLOC + k]] = a * NLOC + k;
  } else {
    int k = (blk - B1) * TPB + threadIdx.x;
    gU[OFF[2 * N + IU_inInd[k]] + tU[14 * NLOC + k]] = 14 * NLOC + k;
    #pragma unroll
    for (int j = 0; j < 5; ++j)
      gU[OFF[2 * N + IU_neighInd[k * 5 + j]] + tU[(9 + j) * NLOC + k]] =
          (9 + j) * NLOC + k;
  }
}

// pass 1: Wm (S2 pairs) / Wc products -> u_all; CSR Lv/rs_cm with 2 threads
// per row (stride-2 walk + shfl combine); pAp
// grid: Bl + Bl + 2*Bn
__global__ void k_it1(const float* __restrict__ p,
                      const float* __restrict__ S2, const int* __restrict__ LOC_inInd,
                      const int* __restrict__ width_p,
                      const float* __restrict__ IU_flows, const int* __restrict__ IU_inInd,
                      const int* __restrict__ IU_neighInd, const float* __restrict__ IUw,
                      const float* __restrict__ diag_ku,
                      const int* __restrict__ OFF, const int2* __restrict__ csrPk,
                      float* __restrict__ u_all,
                      float* __restrict__ Lv, float* __restrict__ rs_cm,
                      float* __restrict__ pAp_t,
                      int NNZ, int NLOC, int N, int B0, int B1)
{
  int blk = blockIdx.x;
  float red = 0.f;
  if (blk < B0) {                       // Wm via symmetric pair coefficients
    int k = blk * TPB + threadIdx.x;
    int wd = *width_p;
    int base = LOC_inInd[k];
    const int offs[9] = {-1 - wd, -1, -1 + wd, -wd, 0, wd, 1 - wd, 1, 1 + wd};
    float pv[9];
    #pragma unroll
    for (int a = 0; a < 9; ++a) pv[a] = p[base + offs[a]];
    float u[9] = {0.f, 0.f, 0.f, 0.f, 0.f, 0.f, 0.f, 0.f, 0.f};
    float qf = 0.f;
    int idx = 0;
    #pragma unroll
    for (int a = 0; a < 9; ++a)
      #pragma unroll
      for (int b = a + 1; b < 9; ++b) {
        float sv = S2[(size_t)idx * NLOC + k];
        ++idx;
        float d = pv[a] - pv[b];
        float t = sv * d;
        u[a] += t; u[b] -= t;
        qf += t * d;
      }
    #pragma unroll
    for (int a = 0; a < 9; ++a) u_all[a * NLOC + k] = u[a];
    red = qf;
  } else if (blk < B1) {                // Wc
    int k = (blk - B0) * TPB + threadIdx.x;
    int r0 = IU_inInd[k];
    float hw = 0.5f * IUw[r0];
    float pr = p[r0];
    int c[5]; float w[5];
    #pragma unroll
    for (int j = 0; j < 5; ++j) {
      c[j] = IU_neighInd[k * 5 + j];
      w[j] = hw * IU_flows[k * 5 + j];
    }
    float pc[5];
    #pragma unroll
    for (int j = 0; j < 5; ++j) pc[j] = p[c[j]];
    float qf = 0.f, asum = 0.f;
    #pragma unroll
    for (int j = 0; j < 5; ++j) {
      float d = pr - pc[j];
      float uA = w[j] * d;
      u_all[(9 + j) * NLOC + k] = -uA;   // direction B (row c0)
      asum += uA;
      qf += uA * d;
    }
    u_all[14 * NLOC + k] = asum;          // direction A row-sum (row r0)
    red = qf;
  } else {                              // CSR: 2 threads per row, stride-2
    int g = (blk - B1) * TPB + threadIdx.x;   // 0 .. 2N-1
    int i = g >> 1, sub = g & 1;
    float pi = p[i];
    int s = OFF[i];
    int e = (i == N - 1) ? NNZ : OFF[i + 1];
    float acc = 0.f, rs = 0.f;
    int q = s + sub;
    for (; q + 6 < e; q += 8) {           // 4 entries per batch, stride 2
      int2 e0 = csrPk[q], e1 = csrPk[q + 2], e2 = csrPk[q + 4], e3 = csrPk[q + 6];
      float g0 = p[e0.x], g1 = p[e1.x], g2 = p[e2.x], g3 = p[e3.x];
      float c0 = __int_as_float(e0.y), c1 = __int_as_float(e1.y);
      float c2 = __int_as_float(e2.y), c3 = __int_as_float(e3.y);
      rs += (c0 + c1) + (c2 + c3);
      acc += c0 * (pi - g0) + c1 * (pi - g1) + c2 * (pi - g2) + c3 * (pi - g3);
    }
    for (; q < e; q += 2) {
      int2 ed = csrPk[q];
      float cv = __int_as_float(ed.y);
      rs += cv;
      acc += cv * (pi - p[ed.x]);
    }
    acc += __shfl_xor(acc, 1);
    rs  += __shfl_xor(rs, 1);
    if (sub == 0) {
      Lv[i] = acc;
      rs_cm[i] = rs;
      red = diag_ku[i] * pi * pi + acc * acc;
    }
  }
  float v = blockReduce256(red);
  if (threadIdx.x == 0) atomicAdd(pAp_t, v);
}

// pass 2: Ap = diag p + rs_cm Lv - csc_pull(Lv) + unified u-pull; x/r; r.r
// 4 threads per row (stride-4 walks + shfl combine).  grid: 4*Bn
__global__ void k_it2(float* __restrict__ x, float* __restrict__ r,
                      const float* __restrict__ p, const float* __restrict__ Lv,
                      const float* __restrict__ rs_cm, const float* __restrict__ diag_ku,
                      const int* __restrict__ OFF,
                      const int2* __restrict__ cscPk,
                      const int* __restrict__ gU, const float* __restrict__ u_all,
                      const float* __restrict__ rs_t, const float* __restrict__ pAp_t,
                      float* __restrict__ rs_t1,
                      int NNZ, int NLOC, int N)
{
  int g = blockIdx.x * TPB + threadIdx.x;   // 0 .. 4N-1
  int i = g >> 2, sub = g & 3;
  float alpha = rs_t[0] / pAp_t[0];
  // unified u-pull (Wm + WcA + WcB), 2-deep pipeline, stride 4
  float tg = 0.f;
  {
    int s0 = OFF[2 * N + i];
    int e0 = (i == N - 1) ? 15 * NLOC : OFF[2 * N + i + 1];
    int q = s0 + sub;
    for (; q + 4 < e0; q += 8) {
      int a = gU[q], b = gU[q + 4];
      tg += u_all[a] + u_all[b];
    }
    for (; q < e0; q += 4) tg += u_all[gU[q]];
  }
  // CM: W^T Lv via CSC, 2-deep pipeline, stride 4
  float sc = 0.f;
  {
    int s1 = OFF[N + i];
    int e1 = (i == N - 1) ? NNZ : OFF[N + i + 1];
    int q = s1 + sub;
    for (; q + 4 < e1; q += 8) {
      int2 ea = cscPk[q], eb = cscPk[q + 4];
      float la = Lv[ea.x], lb = Lv[eb.x];
      sc += __int_as_float(ea.y) * la + __int_as_float(eb.y) * lb;
    }
    for (; q < e1; q += 4) {
      int2 ed = cscPk[q];
      sc += __int_as_float(ed.y) * Lv[ed.x];
    }
  }
  tg += __shfl_xor(tg, 1); tg += __shfl_xor(tg, 2);
  sc += __shfl_xor(sc, 1); sc += __shfl_xor(sc, 2);
  float red = 0.f;
  if (sub == 0) {
    float pi = p[i];
    float Ap = diag_ku[i] * pi + rs_cm[i] * Lv[i] - sc + tg;
    x[i] += alpha * pi;
    float rn = r[i] - alpha * Ap;
    r[i] = rn;
    red = rn * rn;
  }
  float v = blockReduce256(red);
  if (threadIdx.x == 0) atomicAdd(rs_t1, v);
}

__global__ void k_it3(float* __restrict__ p, const float* __restrict__ r,
                      const float* __restrict__ rs_new, const float* __restrict__ rs_old, int N)
{
  int i = blockIdx.x * TPB + threadIdx.x;
  float beta = rs_new[0] / rs_old[0];
  p[i] = r[i] + beta * p[i];
}

extern "C" void kernel_launch(void* const* d_in, const int* in_sizes, int n_in,
                              void* d_out, int out_size, void* d_ws, size_t ws_size,
                              hipStream_t stream)
{
  const float* CMw       = (const float*)d_in[0];
  const float* LOCw      = (const float*)d_in[1];
  const float* IUw       = (const float*)d_in[2];
  const float* KUw       = (const float*)d_in[3];
  const float* lmbda     = (const float*)d_in[4];
  const float* kToUconf  = (const float*)d_in[5];
  const float* known     = (const float*)d_in[6];
  const float* kToU      = (const float*)d_in[7];
  const float* Wcm_data  = (const float*)d_in[8];
  float*       LOC_flows = (float*)d_in[9];      // overwritten in-place by k_prep;
                                                 // harness restores d_in every launch
  const float* IU_flows  = (const float*)d_in[10];
  const int*   Wrow      = (const int*)d_in[11];
  const int*   Wcol      = (const int*)d_in[12];
  const int*   LOC_inInd = (const int*)d_in[13];
  const int*   IU_inInd  = (const int*)d_in[14];
  const int*   IU_neighInd = (const int*)d_in[15];
  const int*   width_p   = (const int*)d_in[16];
  const int CG_STEPS = 30;

  const int N    = in_sizes[0];      // 147456 (% 256 == 0)
  const int NNZ  = in_sizes[8];      // 1474560
  const int NLOC = in_sizes[13];     // 73728

  // ---- workspace layout, ~40.8 MB (identical to R10) ----
  float* x       = (float*)d_out;
  float* r       = (float*)d_ws;                 // N
  float* p       = r + N;                        // N
  float* Lv      = p + N;                        // N
  float* rs_cm   = Lv + N;                       // N
  float* diag_ku = rs_cm + N;                    // N
  int2*  csrPk   = (int2*)(diag_ku + N);         // NNZ int2
  int2*  cscPk   = csrPk + (size_t)NNZ;          // NNZ int2
  int*   gU      = (int*)(cscPk + (size_t)NNZ);  // 15*NLOC
  int*   OFF     = gU + (size_t)15 * NLOC;       // 3N (in-place CNT -> OFF)
  unsigned short* tr = (unsigned short*)(OFF + (size_t)3 * N);  // NNZ u16
  unsigned short* tc = tr + (size_t)NNZ;         // NNZ u16
  unsigned short* tU = tc + (size_t)NNZ;         // 15*NLOC u16
  float* u_all   = (float*)tr;                   // 15*NLOC floats, aliases tickets
                                                 // (tickets dead after k_fill)
  int*   bsum    = (int*)(tU + (size_t)15 * NLOC);  // 3*(N/256)
  float* scal    = (float*)(bsum + 3 * (N / TPB));  // 80 floats

  const int Bn = N / TPB;        // 576
  const int Bz = NNZ / TPB;      // 5760
  const int Bl = NLOC / TPB;     // 288
  const int Z3 = 3 * Bn;

  k_init0<<<Z3, TPB, 0, stream>>>(KUw, kToUconf, lmbda, known, kToU,
                                  diag_ku, r, p, x, OFF, scal, N);
  k_prep<<<Bl, TPB, 0, stream>>>(LOC_flows, LOC_inInd, LOCw, NLOC);
  k_hist<<<Bz + 2 * Bl, TPB, 0, stream>>>(Wrow, Wcol, LOC_inInd, width_p,
                                          IU_inInd, IU_neighInd, OFF,
                                          tr, tc, tU, NLOC, N, Bz, Bz + Bl);
  k_scan1<<<Z3, TPB, 0, stream>>>(OFF, bsum, 3 * N);
  k_scan2<<<3, 1024, 0, stream>>>(bsum, Bn);
  k_scan3<<<Z3, TPB, 0, stream>>>(OFF, bsum, 3 * N);
  k_fill<<<Bz + 2 * Bl, TPB, 0, stream>>>(CMw, Wcm_data, Wrow, Wcol,
                                          LOC_inInd, width_p, IU_inInd, IU_neighInd,
                                          OFF, tr, tc, tU,
                                          csrPk, cscPk, gU,
                                          NLOC, N, Bz, Bz + Bl);

  for (int t = 0; t < CG_STEPS; ++t) {
    k_it1<<<2 * Bl + 2 * Bn, TPB, 0, stream>>>(
        p, LOC_flows, LOC_inInd, width_p,
        IU_flows, IU_inInd, IU_neighInd, IUw,
        diag_ku, OFF, csrPk, u_all, Lv, rs_cm, scal + 40 + t,
        NNZ, NLOC, N, Bl, 2 * Bl);
    k_it2<<<4 * Bn, TPB, 0, stream>>>(
        x, r, p, Lv, rs_cm, diag_ku, OFF, cscPk, gU, u_all,
        scal + t, scal + 40 + t, scal + t + 1, NNZ, NLOC, N);
    if (t + 1 < CG_STEPS)
      k_it3<<<Bn, TPB, 0, stream>>>(p, r, scal + t + 1, scal + t, N);
  }
}

// Round 3
// 2359.729 us; speedup vs baseline: 1.1344x; 1.1344x over previous
//
#include <hip/hip_runtime.h>

// ---------------------------------------------------------------------------
// MattingSolver CG on MI355X — round 13: R10 structure + fused p-update +
// evict-first streams.
//
// R11 (scatter) 2222us, R12 (split-row) 2677us: BOTH regressed vs R10 1879.
// Shared property: more VMEM instructions for same volume -> iteration
// kernels are VMEM/L1-request-throughput bound. R10's 1-row/thread 8-wide
// (4x dwordx4 per 8 entries) is the right shape. R13 keeps it exactly and:
//  * k_it3 ELIMINATED: PR[j]=(p_old,r) float2; beta is a device scalar known
//    at launch -> p[j]=fma(beta,PR.x,PR.y) on the fly. 8B gather = same L1
//    line count as 4B. 2 kernels/iter, 60 launches vs 89.
//  * nt (evict-first) vectorized loads on one-pass streams (csrPk, cscPk,
//    gU, S2, IU_flows): ~28MB/iter of streams stop evicting PR/Lv/u_all
//    from the 4MiB/XCD L2s. Parity-aligned heads keep 16B dwordx4 shape.
// Setup (k_hist atomic wall 158us) untouched.
// ---------------------------------------------------------------------------

#define TPB 256

typedef int v4i __attribute__((ext_vector_type(4)));

__device__ __forceinline__ v4i nt2e(const int2* p) {           // 2 packed entries
  return __builtin_nontemporal_load(reinterpret_cast<const v4i*>(p));
}
__device__ __forceinline__ long long nt1e(const int2* p) {     // 1 packed entry
  return __builtin_nontemporal_load(reinterpret_cast<const long long*>(p));
}
__device__ __forceinline__ v4i nt4i(const int* p) {            // 4 ints
  return __builtin_nontemporal_load(reinterpret_cast<const v4i*>(p));
}

__device__ __forceinline__ float blockReduce256(float v) {
  #pragma unroll
  for (int o = 32; o > 0; o >>= 1) v += __shfl_down(v, o, 64);
  __shared__ float s[4];
  int lane = threadIdx.x & 63, wv = threadIdx.x >> 6;
  if (lane == 0) s[wv] = v;
  __syncthreads();
  return (threadIdx.x == 0) ? (s[0] + s[1] + s[2] + s[3]) : 0.f;
}

// vectors, diag, b, scal, CNT zero, b.b  (grid: 3*Bn)
__global__ void k_init0(const float* __restrict__ KUw, const float* __restrict__ kToUconf,
                        const float* __restrict__ lmbda, const float* __restrict__ known,
                        const float* __restrict__ kToU,
                        float* __restrict__ diag_ku, float2* __restrict__ PR,
                        float* __restrict__ x,
                        int* __restrict__ CNT, float* __restrict__ scal, int N)
{
  int i = blockIdx.x * TPB + threadIdx.x;
  if (i < 80) scal[i] = 0.f;
  if (i < 3 * N) CNT[i] = 0;
  float red = 0.f;
  if (i < N) {
    float dk = KUw[i] * kToUconf[i] + lmbda[0] * known[i];
    diag_ku[i] = dk;
    float b = dk * kToU[i];
    PR[i] = make_float2(b, b);   // (p_old, r); first iter beta=0 -> p = r = b
    x[i] = 0.f;
    red = b * b;
  }
  float v = blockReduce256(red);
  if (threadIdx.x == 0) atomicAdd(&scal[0], v);
}

// in-place symmetrization: LOC_flows rows 0..35 <- 0.5*w*(F_ab+F_ba), a<b.
// Thread k owns column k; harness restores d_in before every launch.
__global__ void k_prep(float* __restrict__ LOC_flows, const int* __restrict__ LOC_inInd,
                       const float* __restrict__ LOCw, int NLOC)
{
  int k = blockIdx.x * TPB + threadIdx.x;
  float Fl[81];
  #pragma unroll
  for (int m = 0; m < 81; ++m) Fl[m] = LOC_flows[(size_t)m * NLOC + k];
  float hw = 0.5f * LOCw[LOC_inInd[k]];
  int idx = 0;
  #pragma unroll
  for (int a = 0; a < 9; ++a)
    #pragma unroll
    for (int b = a + 1; b < 9; ++b) {
      LOC_flows[(size_t)idx * NLOC + k] = hw * (Fl[a * 9 + b] + Fl[b * 9 + a]);
      ++idx;
    }
}

// histograms + tickets  (grid: Bz + Bl + Bl)
__global__ void k_hist(const int* __restrict__ Wrow, const int* __restrict__ Wcol,
                       const int* __restrict__ LOC_inInd, const int* __restrict__ width_p,
                       const int* __restrict__ IU_inInd, const int* __restrict__ IU_neighInd,
                       int* __restrict__ CNT,
                       unsigned short* __restrict__ tr, unsigned short* __restrict__ tc,
                       unsigned short* __restrict__ tU,
                       int NLOC, int N, int B0, int B1)
{
  int blk = blockIdx.x;
  if (blk < B0) {
    int e = blk * TPB + threadIdx.x;
    tr[e] = (unsigned short)atomicAdd(&CNT[Wrow[e]], 1);
    tc[e] = (unsigned short)atomicAdd(&CNT[N + Wcol[e]], 1);
  } else if (blk < B1) {                // Wm: (k,a) by out-row
    int k = (blk - B0) * TPB + threadIdx.x;
    int wd = *width_p;
    int base = LOC_inInd[k];
    const int offs[9] = {-1 - wd, -1, -1 + wd, -wd, 0, wd, 1 - wd, 1, 1 + wd};
    #pragma unroll
    for (int a = 0; a < 9; ++a)
      tU[a * NLOC + k] = (unsigned short)atomicAdd(&CNT[2 * N + base + offs[a]], 1);
  } else {                              // Wc: dirA k by r0, dirB (k,j) by c0
    int k = (blk - B1) * TPB + threadIdx.x;
    tU[14 * NLOC + k] = (unsigned short)atomicAdd(&CNT[2 * N + IU_inInd[k]], 1);
    #pragma unroll
    for (int j = 0; j < 5; ++j)
      tU[(9 + j) * NLOC + k] =
          (unsigned short)atomicAdd(&CNT[2 * N + IU_neighInd[k * 5 + j]], 1);
  }
}

// in-place exclusive scan (OFF==CNT)
__global__ void k_scan1(int* __restrict__ OFF, int* __restrict__ bsum, int tot)
{
  __shared__ int s[TPB];
  int gid = blockIdx.x * TPB + threadIdx.x;
  int v = (gid < tot) ? OFF[gid] : 0;
  s[threadIdx.x] = v;
  __syncthreads();
  #pragma unroll
  for (int o = 1; o < TPB; o <<= 1) {
    int t = (threadIdx.x >= o) ? s[threadIdx.x - o] : 0;
    __syncthreads();
    s[threadIdx.x] += t;
    __syncthreads();
  }
  if (gid < tot) OFF[gid] = s[threadIdx.x] - v;
  if (threadIdx.x == TPB - 1) bsum[blockIdx.x] = s[threadIdx.x];
}

__global__ void k_scan2(int* __restrict__ bsum, int nPerArr)  // 3 blocks x 1024
{
  __shared__ int s[1024];
  int base = blockIdx.x * nPerArr;
  int v = (threadIdx.x < nPerArr) ? bsum[base + threadIdx.x] : 0;
  s[threadIdx.x] = v;
  __syncthreads();
  for (int o = 1; o < 1024; o <<= 1) {
    int t = (threadIdx.x >= o) ? s[threadIdx.x - o] : 0;
    __syncthreads();
    s[threadIdx.x] += t;
    __syncthreads();
  }
  if (threadIdx.x < nPerArr) bsum[base + threadIdx.x] = s[threadIdx.x] - v;
}

__global__ void k_scan3(int* __restrict__ OFF, const int* __restrict__ bsum, int tot)
{
  int gid = blockIdx.x * TPB + threadIdx.x;
  if (gid < tot) OFF[gid] += bsum[blockIdx.x];
}

// atomic-free fill: pos = OFF[key] + ticket  (grid: Bz + Bl + Bl)
__global__ void k_fill(const float* __restrict__ CMw, const float* __restrict__ Wcm_data,
                       const int* __restrict__ Wrow, const int* __restrict__ Wcol,
                       const int* __restrict__ LOC_inInd, const int* __restrict__ width_p,
                       const int* __restrict__ IU_inInd, const int* __restrict__ IU_neighInd,
                       const int* __restrict__ OFF,
                       const unsigned short* __restrict__ tr, const unsigned short* __restrict__ tc,
                       const unsigned short* __restrict__ tU,
                       int2* __restrict__ csrPk, int2* __restrict__ cscPk,
                       int* __restrict__ gU,
                       int NLOC, int N, int B0, int B1)
{
  int blk = blockIdx.x;
  if (blk < B0) {
    int e = blk * TPB + threadIdx.x;
    int row = Wrow[e], col = Wcol[e];
    int cv = __float_as_int(CMw[row] * Wcm_data[e]);
    csrPk[OFF[row] + tr[e]] = make_int2(col, cv);
    cscPk[OFF[N + col] + tc[e]] = make_int2(row, cv);
  } else if (blk < B1) {
    int k = (blk - B0) * TPB + threadIdx.x;
    int wd = *width_p;
    int base = LOC_inInd[k];
    const int offs[9] = {-1 - wd, -1, -1 + wd, -wd, 0, wd, 1 - wd, 1, 1 + wd};
    #pragma unroll
    for (int a = 0; a < 9; ++a)
      gU[OFF[2 * N + base + offs[a]] + tU[a * NLOC + k]] = a * NLOC + k;
  } else {
    int k = (blk - B1) * TPB + threadIdx.x;
    gU[OFF[2 * N + IU_inInd[k]] + tU[14 * NLOC + k]] = 14 * NLOC + k;
    #pragma unroll
    for (int j = 0; j < 5; ++j)
      gU[OFF[2 * N + IU_neighInd[k * 5 + j]] + tU[(9 + j) * NLOC + k]] =
          (9 + j) * NLOC + k;
  }
}

// pass 1: p = fma(beta, p_old, r) on the fly from PR; Wm/Wc -> u_all;
// CSR Lv/rs_cm (8-wide nt); pAp.  grid: Bl + Bl + Bn
__global__ void k_it1(const float2* __restrict__ PR,
                      const float* __restrict__ S2, const int* __restrict__ LOC_inInd,
                      const int* __restrict__ width_p,
                      const float* __restrict__ IU_flows, const int* __restrict__ IU_inInd,
                      const int* __restrict__ IU_neighInd, const float* __restrict__ IUw,
                      const float* __restrict__ diag_ku,
                      const int* __restrict__ OFF, const int2* __restrict__ csrPk,
                      float* __restrict__ u_all,
                      float* __restrict__ Lv, float* __restrict__ rs_cm,
                      const float* __restrict__ rsN, const float* __restrict__ rsO, int first,
                      float* __restrict__ pAp_t,
                      int NNZ, int NLOC, int N, int B0, int B1)
{
  int blk = blockIdx.x;
  float beta = first ? 0.f : rsN[0] / rsO[0];
  float red = 0.f;
  if (blk < B0) {                       // Wm via symmetric pair coefficients
    int k = blk * TPB + threadIdx.x;
    int wd = *width_p;
    int base = LOC_inInd[k];
    const int offs[9] = {-1 - wd, -1, -1 + wd, -wd, 0, wd, 1 - wd, 1, 1 + wd};
    float pv[9];
    #pragma unroll
    for (int a = 0; a < 9; ++a) {
      float2 pr = PR[base + offs[a]];
      pv[a] = __builtin_fmaf(beta, pr.x, pr.y);
    }
    float u[9] = {0.f, 0.f, 0.f, 0.f, 0.f, 0.f, 0.f, 0.f, 0.f};
    float qf = 0.f;
    int idx = 0;
    #pragma unroll
    for (int a = 0; a < 9; ++a)
      #pragma unroll
      for (int b = a + 1; b < 9; ++b) {
        float sv = __builtin_nontemporal_load(&S2[(size_t)idx * NLOC + k]);
        ++idx;
        float d = pv[a] - pv[b];
        float t = sv * d;
        u[a] += t; u[b] -= t;
        qf += t * d;
      }
    #pragma unroll
    for (int a = 0; a < 9; ++a) u_all[a * NLOC + k] = u[a];
    red = qf;
  } else if (blk < B1) {                // Wc
    int k = (blk - B0) * TPB + threadIdx.x;
    int r0 = IU_inInd[k];
    float hw = 0.5f * IUw[r0];
    float2 prr = PR[r0];
    float pr = __builtin_fmaf(beta, prr.x, prr.y);
    int c[5]; float w[5];
    #pragma unroll
    for (int j = 0; j < 5; ++j) {
      c[j] = IU_neighInd[k * 5 + j];
      w[j] = hw * __builtin_nontemporal_load(&IU_flows[k * 5 + j]);
    }
    float pc[5];
    #pragma unroll
    for (int j = 0; j < 5; ++j) {
      float2 pp = PR[c[j]];
      pc[j] = __builtin_fmaf(beta, pp.x, pp.y);
    }
    float qf = 0.f, asum = 0.f;
    #pragma unroll
    for (int j = 0; j < 5; ++j) {
      float d = pr - pc[j];
      float uA = w[j] * d;
      u_all[(9 + j) * NLOC + k] = -uA;   // direction B (row c0)
      asum += uA;
      qf += uA * d;
    }
    u_all[14 * NLOC + k] = asum;          // direction A row-sum (row r0)
    red = qf;
  } else {                              // CSR: Lv = sum cv (p_i - p_c), 8-wide nt
    int i = (blk - B1) * TPB + threadIdx.x;
    float2 pri = PR[i];
    float pi = __builtin_fmaf(beta, pri.x, pri.y);
    int s = OFF[i];
    int e = (i == N - 1) ? NNZ : OFF[i + 1];
    float acc = 0.f, rs = 0.f;
    int q = s;
    if (q < e && (q & 1)) {               // parity head -> 16B-align
      long long L = nt1e(csrPk + q);
      float cv = __int_as_float((int)(L >> 32));
      float2 gg = PR[(int)L];
      rs += cv;
      acc += cv * (pi - __builtin_fmaf(beta, gg.x, gg.y));
      ++q;
    }
    for (; q + 8 <= e; q += 8) {
      v4i w0 = nt2e(csrPk + q),     w1 = nt2e(csrPk + q + 2);
      v4i w2 = nt2e(csrPk + q + 4), w3 = nt2e(csrPk + q + 6);
      float2 g0 = PR[w0[0]], g1 = PR[w0[2]], g2 = PR[w1[0]], g3 = PR[w1[2]];
      float2 g4 = PR[w2[0]], g5 = PR[w2[2]], g6 = PR[w3[0]], g7 = PR[w3[2]];
      float c0 = __int_as_float(w0[1]), c1 = __int_as_float(w0[3]);
      float c2 = __int_as_float(w1[1]), c3 = __int_as_float(w1[3]);
      float c4 = __int_as_float(w2[1]), c5 = __int_as_float(w2[3]);
      float c6 = __int_as_float(w3[1]), c7 = __int_as_float(w3[3]);
      rs += (c0 + c1) + (c2 + c3) + (c4 + c5) + (c6 + c7);
      acc += c0 * (pi - __builtin_fmaf(beta, g0.x, g0.y))
           + c1 * (pi - __builtin_fmaf(beta, g1.x, g1.y))
           + c2 * (pi - __builtin_fmaf(beta, g2.x, g2.y))
           + c3 * (pi - __builtin_fmaf(beta, g3.x, g3.y))
           + c4 * (pi - __builtin_fmaf(beta, g4.x, g4.y))
           + c5 * (pi - __builtin_fmaf(beta, g5.x, g5.y))
           + c6 * (pi - __builtin_fmaf(beta, g6.x, g6.y))
           + c7 * (pi - __builtin_fmaf(beta, g7.x, g7.y));
    }
    for (; q + 2 <= e; q += 2) {
      v4i w0 = nt2e(csrPk + q);
      float2 g0 = PR[w0[0]], g1 = PR[w0[2]];
      float c0 = __int_as_float(w0[1]), c1 = __int_as_float(w0[3]);
      rs += c0 + c1;
      acc += c0 * (pi - __builtin_fmaf(beta, g0.x, g0.y))
           + c1 * (pi - __builtin_fmaf(beta, g1.x, g1.y));
    }
    if (q < e) {
      long long L = nt1e(csrPk + q);
      float cv = __int_as_float((int)(L >> 32));
      float2 gg = PR[(int)L];
      rs += cv;
      acc += cv * (pi - __builtin_fmaf(beta, gg.x, gg.y));
    }
    Lv[i] = acc;
    rs_cm[i] = rs;
    red = diag_ku[i] * pi * pi + acc * acc;
  }
  float v = blockReduce256(red);
  if (threadIdx.x == 0) atomicAdd(pAp_t, v);
}

// pass 2: Ap = diag p + rs_cm Lv - csc_pull(Lv) + u-pull; x += alpha p;
// PR <- (p, r_new); r.r   (grid: Bn)
__global__ void k_it2(float* __restrict__ x, float2* __restrict__ PR,
                      const float* __restrict__ Lv,
                      const float* __restrict__ rs_cm, const float* __restrict__ diag_ku,
                      const int* __restrict__ OFF,
                      const int2* __restrict__ cscPk,
                      const int* __restrict__ gU, const float* __restrict__ u_all,
                      const float* __restrict__ rs_t, const float* __restrict__ pAp_t,
                      const float* __restrict__ rsO, int first,
                      float* __restrict__ rs_t1,
                      int NNZ, int NLOC, int N)
{
  int i = blockIdx.x * TPB + threadIdx.x;
  float alpha = rs_t[0] / pAp_t[0];
  float beta = first ? 0.f : rs_t[0] / rsO[0];
  // unified u-pull (Wm + WcA + WcB), nt 8/4/1-wide
  float tg = 0.f;
  {
    int q = OFF[2 * N + i];
    int e0 = (i == N - 1) ? 15 * NLOC : OFF[2 * N + i + 1];
    for (; q < e0 && (q & 3); ++q)
      tg += u_all[__builtin_nontemporal_load(gU + q)];
    for (; q + 8 <= e0; q += 8) {
      v4i a = nt4i(gU + q), b = nt4i(gU + q + 4);
      tg += ((u_all[a[0]] + u_all[a[1]]) + (u_all[a[2]] + u_all[a[3]]))
          + ((u_all[b[0]] + u_all[b[1]]) + (u_all[b[2]] + u_all[b[3]]));
    }
    for (; q + 4 <= e0; q += 4) {
      v4i a = nt4i(gU + q);
      tg += (u_all[a[0]] + u_all[a[1]]) + (u_all[a[2]] + u_all[a[3]]);
    }
    for (; q < e0; ++q)
      tg += u_all[__builtin_nontemporal_load(gU + q)];
  }
  // CM: W^T Lv via CSC, nt 8/2/1-wide
  float sc = 0.f;
  {
    int q = OFF[N + i];
    int e1 = (i == N - 1) ? NNZ : OFF[N + i + 1];
    if (q < e1 && (q & 1)) {
      long long L = nt1e(cscPk + q);
      sc += __int_as_float((int)(L >> 32)) * Lv[(int)L];
      ++q;
    }
    for (; q + 8 <= e1; q += 8) {
      v4i w0 = nt2e(cscPk + q),     w1 = nt2e(cscPk + q + 2);
      v4i w2 = nt2e(cscPk + q + 4), w3 = nt2e(cscPk + q + 6);
      float l0 = Lv[w0[0]], l1 = Lv[w0[2]], l2 = Lv[w1[0]], l3 = Lv[w1[2]];
      float l4 = Lv[w2[0]], l5 = Lv[w2[2]], l6 = Lv[w3[0]], l7 = Lv[w3[2]];
      sc += __int_as_float(w0[1]) * l0 + __int_as_float(w0[3]) * l1
          + __int_as_float(w1[1]) * l2 + __int_as_float(w1[3]) * l3
          + __int_as_float(w2[1]) * l4 + __int_as_float(w2[3]) * l5
          + __int_as_float(w3[1]) * l6 + __int_as_float(w3[3]) * l7;
    }
    for (; q + 2 <= e1; q += 2) {
      v4i w0 = nt2e(cscPk + q);
      sc += __int_as_float(w0[1]) * Lv[w0[0]]
          + __int_as_float(w0[3]) * Lv[w0[2]];
    }
    if (q < e1) {
      long long L = nt1e(cscPk + q);
      sc += __int_as_float((int)(L >> 32)) * Lv[(int)L];
    }
  }
  float2 pri = PR[i];
  float pi = __builtin_fmaf(beta, pri.x, pri.y);
  float Ap = diag_ku[i] * pi + rs_cm[i] * Lv[i] - sc + tg;
  x[i] += alpha * pi;
  float rn = pri.y - alpha * Ap;
  PR[i] = make_float2(pi, rn);          // (p_old, r) for next iteration
  float v = blockReduce256(rn * rn);
  if (threadIdx.x == 0) atomicAdd(rs_t1, v);
}

extern "C" void kernel_launch(void* const* d_in, const int* in_sizes, int n_in,
                              void* d_out, int out_size, void* d_ws, size_t ws_size,
                              hipStream_t stream)
{
  const float* CMw       = (const float*)d_in[0];
  const float* LOCw      = (const float*)d_in[1];
  const float* IUw       = (const float*)d_in[2];
  const float* KUw       = (const float*)d_in[3];
  const float* lmbda     = (const float*)d_in[4];
  const float* kToUconf  = (const float*)d_in[5];
  const float* known     = (const float*)d_in[6];
  const float* kToU      = (const float*)d_in[7];
  const float* Wcm_data  = (const float*)d_in[8];
  float*       LOC_flows = (float*)d_in[9];      // overwritten in-place by k_prep;
                                                 // harness restores d_in every launch
  const float* IU_flows  = (const float*)d_in[10];
  const int*   Wrow      = (const int*)d_in[11];
  const int*   Wcol      = (const int*)d_in[12];
  const int*   LOC_inInd = (const int*)d_in[13];
  const int*   IU_inInd  = (const int*)d_in[14];
  const int*   IU_neighInd = (const int*)d_in[15];
  const int*   width_p   = (const int*)d_in[16];
  const int CG_STEPS = 30;

  const int N    = in_sizes[0];      // 147456 (% 256 == 0)
  const int NNZ  = in_sizes[8];      // 1474560
  const int NLOC = in_sizes[13];     // 73728

  // ---- workspace layout, ~40.8 MB (PR replaces r+p; otherwise R10) ----
  float* x       = (float*)d_out;
  float2* PR     = (float2*)d_ws;                // N float2 (p_old, r)
  float* Lv      = (float*)(PR + (size_t)N);     // N
  float* rs_cm   = Lv + N;                       // N
  float* diag_ku = rs_cm + N;                    // N
  int2*  csrPk   = (int2*)(diag_ku + N);         // NNZ int2
  int2*  cscPk   = csrPk + (size_t)NNZ;          // NNZ int2
  int*   gU      = (int*)(cscPk + (size_t)NNZ);  // 15*NLOC
  int*   OFF     = gU + (size_t)15 * NLOC;       // 3N (in-place CNT -> OFF)
  unsigned short* tr = (unsigned short*)(OFF + (size_t)3 * N);  // NNZ u16
  unsigned short* tc = tr + (size_t)NNZ;         // NNZ u16
  unsigned short* tU = tc + (size_t)NNZ;         // 15*NLOC u16
  float* u_all   = (float*)tr;                   // 15*NLOC floats, aliases tickets
                                                 // (tickets dead after k_fill)
  int*   bsum    = (int*)(tU + (size_t)15 * NLOC);  // 3*(N/256)
  float* scal    = (float*)(bsum + 3 * (N / TPB));  // 80 floats

  const int Bn = N / TPB;        // 576
  const int Bz = NNZ / TPB;      // 5760
  const int Bl = NLOC / TPB;     // 288
  const int Z3 = 3 * Bn;

  k_init0<<<Z3, TPB, 0, stream>>>(KUw, kToUconf, lmbda, known, kToU,
                                  diag_ku, PR, x, OFF, scal, N);
  k_prep<<<Bl, TPB, 0, stream>>>(LOC_flows, LOC_inInd, LOCw, NLOC);
  k_hist<<<Bz + 2 * Bl, TPB, 0, stream>>>(Wrow, Wcol, LOC_inInd, width_p,
                                          IU_inInd, IU_neighInd, OFF,
                                          tr, tc, tU, NLOC, N, Bz, Bz + Bl);
  k_scan1<<<Z3, TPB, 0, stream>>>(OFF, bsum, 3 * N);
  k_scan2<<<3, 1024, 0, stream>>>(bsum, Bn);
  k_scan3<<<Z3, TPB, 0, stream>>>(OFF, bsum, 3 * N);
  k_fill<<<Bz + 2 * Bl, TPB, 0, stream>>>(CMw, Wcm_data, Wrow, Wcol,
                                          LOC_inInd, width_p, IU_inInd, IU_neighInd,
                                          OFF, tr, tc, tU,
                                          csrPk, cscPk, gU,
                                          NLOC, N, Bz, Bz + Bl);

  for (int t = 0; t < CG_STEPS; ++t) {
    const float* rsN = scal + t;
    const float* rsO = scal + (t == 0 ? 0 : t - 1);
    k_it1<<<2 * Bl + Bn, TPB, 0, stream>>>(
        PR, LOC_flows, LOC_inInd, width_p,
        IU_flows, IU_inInd, IU_neighInd, IUw,
        diag_ku, OFF, csrPk, u_all, Lv, rs_cm,
        rsN, rsO, (t == 0) ? 1 : 0, scal + 40 + t,
        NNZ, NLOC, N, Bl, 2 * Bl);
    k_it2<<<Bn, TPB, 0, stream>>>(
        x, PR, Lv, rs_cm, diag_ku, OFF, cscPk, gU, u_all,
        rsN, scal + 40 + t, rsO, (t == 0) ? 1 : 0, scal + t + 1,
        NNZ, NLOC, N);
  }
}

// Round 4
// 1812.062 us; speedup vs baseline: 1.4773x; 1.3022x over previous
//
#include <hip/hip_runtime.h>

// ---------------------------------------------------------------------------
// MattingSolver CG on MI355X — round 14: R10 exact loop shapes + PR fusion
// ONLY (decomposing R13's confounded regression).
//
// History: R10=1879 (best). R11 scatter=2222. R12 split-row=2677.
// R13 (PR fusion + nt loads + parity heads)=2360 — confounded.
// Theory: nt was the poison (streams are L3-resident across 30 iters;
// evict-first refetches ~40MB/iter from HBM ≈ +190us; parity heads broke
// the proven 8-wide load shape). PR fusion alone should win: same gather
// line count, +1 free FMA, kills 29 launches + 29 N-sized RMW passes.
// R14 = R10 verbatim except:
//  * PR[j]=(p_old, r) float2; p=fma(beta,PR.x,PR.y) on the fly.
//  * k_it3 eliminated (62 launches vs 89).
// All stream loops are R10's exact int2[8]/int[8] plain-load form.
// Setup (k_hist atomic wall 159us) untouched.
// ---------------------------------------------------------------------------

#define TPB 256

__device__ __forceinline__ float blockReduce256(float v) {
  #pragma unroll
  for (int o = 32; o > 0; o >>= 1) v += __shfl_down(v, o, 64);
  __shared__ float s[4];
  int lane = threadIdx.x & 63, wv = threadIdx.x >> 6;
  if (lane == 0) s[wv] = v;
  __syncthreads();
  return (threadIdx.x == 0) ? (s[0] + s[1] + s[2] + s[3]) : 0.f;
}

// vectors, diag, b, scal, CNT zero, b.b  (grid: 3*Bn)
__global__ void k_init0(const float* __restrict__ KUw, const float* __restrict__ kToUconf,
                        const float* __restrict__ lmbda, const float* __restrict__ known,
                        const float* __restrict__ kToU,
                        float* __restrict__ diag_ku, float2* __restrict__ PR,
                        float* __restrict__ x,
                        int* __restrict__ CNT, float* __restrict__ scal, int N)
{
  int i = blockIdx.x * TPB + threadIdx.x;
  if (i < 80) scal[i] = 0.f;
  if (i < 3 * N) CNT[i] = 0;
  float red = 0.f;
  if (i < N) {
    float dk = KUw[i] * kToUconf[i] + lmbda[0] * known[i];
    diag_ku[i] = dk;
    float b = dk * kToU[i];
    PR[i] = make_float2(b, b);   // (p_old, r); first iter beta=0 -> p = r = b
    x[i] = 0.f;
    red = b * b;
  }
  float v = blockReduce256(red);
  if (threadIdx.x == 0) atomicAdd(&scal[0], v);
}

// in-place symmetrization: LOC_flows rows 0..35 <- 0.5*w*(F_ab+F_ba), a<b.
// Thread k owns column k; harness restores d_in before every launch.
__global__ void k_prep(float* __restrict__ LOC_flows, const int* __restrict__ LOC_inInd,
                       const float* __restrict__ LOCw, int NLOC)
{
  int k = blockIdx.x * TPB + threadIdx.x;
  float Fl[81];
  #pragma unroll
  for (int m = 0; m < 81; ++m) Fl[m] = LOC_flows[(size_t)m * NLOC + k];
  float hw = 0.5f * LOCw[LOC_inInd[k]];
  int idx = 0;
  #pragma unroll
  for (int a = 0; a < 9; ++a)
    #pragma unroll
    for (int b = a + 1; b < 9; ++b) {
      LOC_flows[(size_t)idx * NLOC + k] = hw * (Fl[a * 9 + b] + Fl[b * 9 + a]);
      ++idx;
    }
}

// histograms + tickets  (grid: Bz + Bl + Bl)
__global__ void k_hist(const int* __restrict__ Wrow, const int* __restrict__ Wcol,
                       const int* __restrict__ LOC_inInd, const int* __restrict__ width_p,
                       const int* __restrict__ IU_inInd, const int* __restrict__ IU_neighInd,
                       int* __restrict__ CNT,
                       unsigned short* __restrict__ tr, unsigned short* __restrict__ tc,
                       unsigned short* __restrict__ tU,
                       int NLOC, int N, int B0, int B1)
{
  int blk = blockIdx.x;
  if (blk < B0) {
    int e = blk * TPB + threadIdx.x;
    tr[e] = (unsigned short)atomicAdd(&CNT[Wrow[e]], 1);
    tc[e] = (unsigned short)atomicAdd(&CNT[N + Wcol[e]], 1);
  } else if (blk < B1) {                // Wm: (k,a) by out-row
    int k = (blk - B0) * TPB + threadIdx.x;
    int wd = *width_p;
    int base = LOC_inInd[k];
    const int offs[9] = {-1 - wd, -1, -1 + wd, -wd, 0, wd, 1 - wd, 1, 1 + wd};
    #pragma unroll
    for (int a = 0; a < 9; ++a)
      tU[a * NLOC + k] = (unsigned short)atomicAdd(&CNT[2 * N + base + offs[a]], 1);
  } else {                              // Wc: dirA k by r0, dirB (k,j) by c0
    int k = (blk - B1) * TPB + threadIdx.x;
    tU[14 * NLOC + k] = (unsigned short)atomicAdd(&CNT[2 * N + IU_inInd[k]], 1);
    #pragma unroll
    for (int j = 0; j < 5; ++j)
      tU[(9 + j) * NLOC + k] =
          (unsigned short)atomicAdd(&CNT[2 * N + IU_neighInd[k * 5 + j]], 1);
  }
}

// in-place exclusive scan (OFF==CNT)
__global__ void k_scan1(int* __restrict__ OFF, int* __restrict__ bsum, int tot)
{
  __shared__ int s[TPB];
  int gid = blockIdx.x * TPB + threadIdx.x;
  int v = (gid < tot) ? OFF[gid] : 0;
  s[threadIdx.x] = v;
  __syncthreads();
  #pragma unroll
  for (int o = 1; o < TPB; o <<= 1) {
    int t = (threadIdx.x >= o) ? s[threadIdx.x - o] : 0;
    __syncthreads();
    s[threadIdx.x] += t;
    __syncthreads();
  }
  if (gid < tot) OFF[gid] = s[threadIdx.x] - v;
  if (threadIdx.x == TPB - 1) bsum[blockIdx.x] = s[threadIdx.x];
}

__global__ void k_scan2(int* __restrict__ bsum, int nPerArr)  // 3 blocks x 1024
{
  __shared__ int s[1024];
  int base = blockIdx.x * nPerArr;
  int v = (threadIdx.x < nPerArr) ? bsum[base + threadIdx.x] : 0;
  s[threadIdx.x] = v;
  __syncthreads();
  for (int o = 1; o < 1024; o <<= 1) {
    int t = (threadIdx.x >= o) ? s[threadIdx.x - o] : 0;
    __syncthreads();
    s[threadIdx.x] += t;
    __syncthreads();
  }
  if (threadIdx.x < nPerArr) bsum[base + threadIdx.x] = s[threadIdx.x] - v;
}

__global__ void k_scan3(int* __restrict__ OFF, const int* __restrict__ bsum, int tot)
{
  int gid = blockIdx.x * TPB + threadIdx.x;
  if (gid < tot) OFF[gid] += bsum[blockIdx.x];
}

// atomic-free fill: pos = OFF[key] + ticket  (grid: Bz + Bl + Bl)
__global__ void k_fill(const float* __restrict__ CMw, const float* __restrict__ Wcm_data,
                       const int* __restrict__ Wrow, const int* __restrict__ Wcol,
                       const int* __restrict__ LOC_inInd, const int* __restrict__ width_p,
                       const int* __restrict__ IU_inInd, const int* __restrict__ IU_neighInd,
                       const int* __restrict__ OFF,
                       const unsigned short* __restrict__ tr, const unsigned short* __restrict__ tc,
                       const unsigned short* __restrict__ tU,
                       int2* __restrict__ csrPk, int2* __restrict__ cscPk,
                       int* __restrict__ gU,
                       int NLOC, int N, int B0, int B1)
{
  int blk = blockIdx.x;
  if (blk < B0) {
    int e = blk * TPB + threadIdx.x;
    int row = Wrow[e], col = Wcol[e];
    int cv = __float_as_int(CMw[row] * Wcm_data[e]);
    csrPk[OFF[row] + tr[e]] = make_int2(col, cv);
    cscPk[OFF[N + col] + tc[e]] = make_int2(row, cv);
  } else if (blk < B1) {
    int k = (blk - B0) * TPB + threadIdx.x;
    int wd = *width_p;
    int base = LOC_inInd[k];
    const int offs[9] = {-1 - wd, -1, -1 + wd, -wd, 0, wd, 1 - wd, 1, 1 + wd};
    #pragma unroll
    for (int a = 0; a < 9; ++a)
      gU[OFF[2 * N + base + offs[a]] + tU[a * NLOC + k]] = a * NLOC + k;
  } else {
    int k = (blk - B1) * TPB + threadIdx.x;
    gU[OFF[2 * N + IU_inInd[k]] + tU[14 * NLOC + k]] = 14 * NLOC + k;
    #pragma unroll
    for (int j = 0; j < 5; ++j)
      gU[OFF[2 * N + IU_neighInd[k * 5 + j]] + tU[(9 + j) * NLOC + k]] =
          (9 + j) * NLOC + k;
  }
}

// pass 1: p = fma(beta, p_old, r) on the fly; Wm/Wc -> u_all; CSR Lv/rs_cm
// (8-wide, R10 shape); pAp.  grid: Bl + Bl + Bn
__global__ void k_it1(const float2* __restrict__ PR,
                      const float* __restrict__ S2, const int* __restrict__ LOC_inInd,
                      const int* __restrict__ width_p,
                      const float* __restrict__ IU_flows, const int* __restrict__ IU_inInd,
                      const int* __restrict__ IU_neighInd, const float* __restrict__ IUw,
                      const float* __restrict__ diag_ku,
                      const int* __restrict__ OFF, const int2* __restrict__ csrPk,
                      float* __restrict__ u_all,
                      float* __restrict__ Lv, float* __restrict__ rs_cm,
                      const float* __restrict__ rsN, const float* __restrict__ rsO, int first,
                      float* __restrict__ pAp_t,
                      int NNZ, int NLOC, int N, int B0, int B1)
{
  int blk = blockIdx.x;
  float beta = first ? 0.f : rsN[0] / rsO[0];
  float red = 0.f;
  if (blk < B0) {                       // Wm via symmetric pair coefficients
    int k = blk * TPB + threadIdx.x;
    int wd = *width_p;
    int base = LOC_inInd[k];
    const int offs[9] = {-1 - wd, -1, -1 + wd, -wd, 0, wd, 1 - wd, 1, 1 + wd};
    float pv[9];
    #pragma unroll
    for (int a = 0; a < 9; ++a) {
      float2 pr = PR[base + offs[a]];
      pv[a] = __builtin_fmaf(beta, pr.x, pr.y);
    }
    float u[9] = {0.f, 0.f, 0.f, 0.f, 0.f, 0.f, 0.f, 0.f, 0.f};
    float qf = 0.f;
    int idx = 0;
    #pragma unroll
    for (int a = 0; a < 9; ++a)
      #pragma unroll
      for (int b = a + 1; b < 9; ++b) {
        float sv = S2[(size_t)idx * NLOC + k];
        ++idx;
        float d = pv[a] - pv[b];
        float t = sv * d;
        u[a] += t; u[b] -= t;
        qf += t * d;
      }
    #pragma unroll
    for (int a = 0; a < 9; ++a) u_all[a * NLOC + k] = u[a];
    red = qf;
  } else if (blk < B1) {                // Wc
    int k = (blk - B0) * TPB + threadIdx.x;
    int r0 = IU_inInd[k];
    float hw = 0.5f * IUw[r0];
    float2 prr = PR[r0];
    float pr = __builtin_fmaf(beta, prr.x, prr.y);
    int c[5]; float w[5];
    #pragma unroll
    for (int j = 0; j < 5; ++j) {
      c[j] = IU_neighInd[k * 5 + j];
      w[j] = hw * IU_flows[k * 5 + j];
    }
    float pc[5];
    #pragma unroll
    for (int j = 0; j < 5; ++j) {
      float2 pp = PR[c[j]];
      pc[j] = __builtin_fmaf(beta, pp.x, pp.y);
    }
    float qf = 0.f, asum = 0.f;
    #pragma unroll
    for (int j = 0; j < 5; ++j) {
      float d = pr - pc[j];
      float uA = w[j] * d;
      u_all[(9 + j) * NLOC + k] = -uA;   // direction B (row c0)
      asum += uA;
      qf += uA * d;
    }
    u_all[14 * NLOC + k] = asum;          // direction A row-sum (row r0)
    red = qf;
  } else {                              // CSR: Lv = sum cv (p_i - p_c), 8-wide
    int i = (blk - B1) * TPB + threadIdx.x;
    float2 pri = PR[i];
    float pi = __builtin_fmaf(beta, pri.x, pri.y);
    int s = OFF[i];
    int e = (i == N - 1) ? NNZ : OFF[i + 1];
    float acc = 0.f, rs = 0.f;
    int q = s;
    for (; q + 8 <= e; q += 8) {
      int2 ed[8];
      #pragma unroll
      for (int m = 0; m < 8; ++m) ed[m] = csrPk[q + m];
      float g[8];
      #pragma unroll
      for (int m = 0; m < 8; ++m) {
        float2 pp = PR[ed[m].x];
        g[m] = __builtin_fmaf(beta, pp.x, pp.y);
      }
      #pragma unroll
      for (int m = 0; m < 8; ++m) {
        float cv = __int_as_float(ed[m].y);
        rs += cv;
        acc += cv * (pi - g[m]);
      }
    }
    for (; q + 4 <= e; q += 4) {
      int2 ed[4];
      #pragma unroll
      for (int m = 0; m < 4; ++m) ed[m] = csrPk[q + m];
      float g[4];
      #pragma unroll
      for (int m = 0; m < 4; ++m) {
        float2 pp = PR[ed[m].x];
        g[m] = __builtin_fmaf(beta, pp.x, pp.y);
      }
      #pragma unroll
      for (int m = 0; m < 4; ++m) {
        float cv = __int_as_float(ed[m].y);
        rs += cv;
        acc += cv * (pi - g[m]);
      }
    }
    for (; q < e; ++q) {
      int2 ed = csrPk[q];
      float cv = __int_as_float(ed.y);
      float2 pp = PR[ed.x];
      rs += cv;
      acc += cv * (pi - __builtin_fmaf(beta, pp.x, pp.y));
    }
    Lv[i] = acc;
    rs_cm[i] = rs;
    red = diag_ku[i] * pi * pi + acc * acc;
  }
  float v = blockReduce256(red);
  if (threadIdx.x == 0) atomicAdd(pAp_t, v);
}

// pass 2: Ap = diag p + rs_cm Lv - csc_pull(Lv) + u-pull; x += alpha p;
// PR <- (p, r_new); r.r   (grid: Bn; R10 loop shapes)
__global__ void k_it2(float* __restrict__ x, float2* __restrict__ PR,
                      const float* __restrict__ Lv,
                      const float* __restrict__ rs_cm, const float* __restrict__ diag_ku,
                      const int* __restrict__ OFF,
                      const int2* __restrict__ cscPk,
                      const int* __restrict__ gU, const float* __restrict__ u_all,
                      const float* __restrict__ rs_t, const float* __restrict__ pAp_t,
                      const float* __restrict__ rsO, int first,
                      float* __restrict__ rs_t1,
                      int NNZ, int NLOC, int N)
{
  int i = blockIdx.x * TPB + threadIdx.x;
  float alpha = rs_t[0] / pAp_t[0];
  float beta = first ? 0.f : rs_t[0] / rsO[0];
  // unified u-pull (Wm + WcA + WcB), 8/4/1-wide
  float tg = 0.f;
  {
    int s0 = OFF[2 * N + i];
    int e0 = (i == N - 1) ? 15 * NLOC : OFF[2 * N + i + 1];
    int q = s0;
    for (; q + 8 <= e0; q += 8) {
      int g[8];
      #pragma unroll
      for (int m = 0; m < 8; ++m) g[m] = gU[q + m];
      float u[8];
      #pragma unroll
      for (int m = 0; m < 8; ++m) u[m] = u_all[g[m]];
      #pragma unroll
      for (int m = 0; m < 8; ++m) tg += u[m];
    }
    for (; q + 4 <= e0; q += 4) {
      int g[4];
      #pragma unroll
      for (int m = 0; m < 4; ++m) g[m] = gU[q + m];
      float u[4];
      #pragma unroll
      for (int m = 0; m < 4; ++m) u[m] = u_all[g[m]];
      #pragma unroll
      for (int m = 0; m < 4; ++m) tg += u[m];
    }
    for (; q < e0; ++q) tg += u_all[gU[q]];
  }
  // CM: W^T Lv via CSC, 8/4/1-wide
  float sc = 0.f;
  {
    int s0 = OFF[N + i];
    int e0 = (i == N - 1) ? NNZ : OFF[N + i + 1];
    int q = s0;
    for (; q + 8 <= e0; q += 8) {
      int2 ed[8];
      #pragma unroll
      for (int m = 0; m < 8; ++m) ed[m] = cscPk[q + m];
      float l[8];
      #pragma unroll
      for (int m = 0; m < 8; ++m) l[m] = Lv[ed[m].x];
      #pragma unroll
      for (int m = 0; m < 8; ++m) sc += __int_as_float(ed[m].y) * l[m];
    }
    for (; q + 4 <= e0; q += 4) {
      int2 ed[4];
      #pragma unroll
      for (int m = 0; m < 4; ++m) ed[m] = cscPk[q + m];
      float l[4];
      #pragma unroll
      for (int m = 0; m < 4; ++m) l[m] = Lv[ed[m].x];
      #pragma unroll
      for (int m = 0; m < 4; ++m) sc += __int_as_float(ed[m].y) * l[m];
    }
    for (; q < e0; ++q) {
      int2 ed = cscPk[q];
      sc += __int_as_float(ed.y) * Lv[ed.x];
    }
  }
  float2 pri = PR[i];
  float pi = __builtin_fmaf(beta, pri.x, pri.y);
  float Ap = diag_ku[i] * pi + rs_cm[i] * Lv[i] - sc + tg;
  x[i] += alpha * pi;
  float rn = pri.y - alpha * Ap;
  PR[i] = make_float2(pi, rn);          // (p_old, r) for next iteration
  float v = blockReduce256(rn * rn);
  if (threadIdx.x == 0) atomicAdd(rs_t1, v);
}

extern "C" void kernel_launch(void* const* d_in, const int* in_sizes, int n_in,
                              void* d_out, int out_size, void* d_ws, size_t ws_size,
                              hipStream_t stream)
{
  const float* CMw       = (const float*)d_in[0];
  const float* LOCw      = (const float*)d_in[1];
  const float* IUw       = (const float*)d_in[2];
  const float* KUw       = (const float*)d_in[3];
  const float* lmbda     = (const float*)d_in[4];
  const float* kToUconf  = (const float*)d_in[5];
  const float* known     = (const float*)d_in[6];
  const float* kToU      = (const float*)d_in[7];
  const float* Wcm_data  = (const float*)d_in[8];
  float*       LOC_flows = (float*)d_in[9];      // overwritten in-place by k_prep;
                                                 // harness restores d_in every launch
  const float* IU_flows  = (const float*)d_in[10];
  const int*   Wrow      = (const int*)d_in[11];
  const int*   Wcol      = (const int*)d_in[12];
  const int*   LOC_inInd = (const int*)d_in[13];
  const int*   IU_inInd  = (const int*)d_in[14];
  const int*   IU_neighInd = (const int*)d_in[15];
  const int*   width_p   = (const int*)d_in[16];
  const int CG_STEPS = 30;

  const int N    = in_sizes[0];      // 147456 (% 256 == 0)
  const int NNZ  = in_sizes[8];      // 1474560
  const int NLOC = in_sizes[13];     // 73728

  // ---- workspace layout, ~40.8 MB (PR replaces r+p; otherwise R10) ----
  float* x       = (float*)d_out;
  float2* PR     = (float2*)d_ws;                // N float2 (p_old, r)
  float* Lv      = (float*)(PR + (size_t)N);     // N
  float* rs_cm   = Lv + N;                       // N
  float* diag_ku = rs_cm + N;                    // N
  int2*  csrPk   = (int2*)(diag_ku + N);         // NNZ int2
  int2*  cscPk   = csrPk + (size_t)NNZ;          // NNZ int2
  int*   gU      = (int*)(cscPk + (size_t)NNZ);  // 15*NLOC
  int*   OFF     = gU + (size_t)15 * NLOC;       // 3N (in-place CNT -> OFF)
  unsigned short* tr = (unsigned short*)(OFF + (size_t)3 * N);  // NNZ u16
  unsigned short* tc = tr + (size_t)NNZ;         // NNZ u16
  unsigned short* tU = tc + (size_t)NNZ;         // 15*NLOC u16
  float* u_all   = (float*)tr;                   // 15*NLOC floats, aliases tickets
                                                 // (tickets dead after k_fill)
  int*   bsum    = (int*)(tU + (size_t)15 * NLOC);  // 3*(N/256)
  float* scal    = (float*)(bsum + 3 * (N / TPB));  // 80 floats

  const int Bn = N / TPB;        // 576
  const int Bz = NNZ / TPB;      // 5760
  const int Bl = NLOC / TPB;     // 288
  const int Z3 = 3 * Bn;

  k_init0<<<Z3, TPB, 0, stream>>>(KUw, kToUconf, lmbda, known, kToU,
                                  diag_ku, PR, x, OFF, scal, N);
  k_prep<<<Bl, TPB, 0, stream>>>(LOC_flows, LOC_inInd, LOCw, NLOC);
  k_hist<<<Bz + 2 * Bl, TPB, 0, stream>>>(Wrow, Wcol, LOC_inInd, width_p,
                                          IU_inInd, IU_neighInd, OFF,
                                          tr, tc, tU, NLOC, N, Bz, Bz + Bl);
  k_scan1<<<Z3, TPB, 0, stream>>>(OFF, bsum, 3 * N);
  k_scan2<<<3, 1024, 0, stream>>>(bsum, Bn);
  k_scan3<<<Z3, TPB, 0, stream>>>(OFF, bsum, 3 * N);
  k_fill<<<Bz + 2 * Bl, TPB, 0, stream>>>(CMw, Wcm_data, Wrow, Wcol,
                                          LOC_inInd, width_p, IU_inInd, IU_neighInd,
                                          OFF, tr, tc, tU,
                                          csrPk, cscPk, gU,
                                          NLOC, N, Bz, Bz + Bl);

  for (int t = 0; t < CG_STEPS; ++t) {
    const float* rsN = scal + t;
    const float* rsO = scal + (t == 0 ? 0 : t - 1);
    k_it1<<<2 * Bl + Bn, TPB, 0, stream>>>(
        PR, LOC_flows, LOC_inInd, width_p,
        IU_flows, IU_inInd, IU_neighInd, IUw,
        diag_ku, OFF, csrPk, u_all, Lv, rs_cm,
        rsN, rsO, (t == 0) ? 1 : 0, scal + 40 + t,
        NNZ, NLOC, N, Bl, 2 * Bl);
    k_it2<<<Bn, TPB, 0, stream>>>(
        x, PR, Lv, rs_cm, diag_ku, OFF, cscPk, gU, u_all,
        rsN, scal + 40 + t, rsO, (t == 0) ? 1 : 0, scal + t + 1,
        NNZ, NLOC, N);
  }
}

// Round 5
// 1781.056 us; speedup vs baseline: 1.5030x; 1.0174x over previous
//
#include <hip/hip_runtime.h>

// ---------------------------------------------------------------------------
// MattingSolver CG on MI355X — round 15: R14 + pixel-sorted Wm pipeline.
//
// R14 (PR fusion) = 1812us, best. rocprof: k_it2 FETCH_SIZE=35.8MB/dispatch
// >> its 16MB partitioned streams -> the small gather arrays (u_all, Lv, PR)
// are fetched ~8x, once per XCD L2 (random gathers touch everything from
// every XCD). Iterations are L2-miss-concurrency bound on this duplicated
// fetch (also explains R12: more waves didn't help).
// R15: bucket-sort unknowns by LOC_inInd (576 buckets, one-time) and run the
// ENTIRE Wm pipeline (hist/fill/it1) in permuted order kp:
//  * it1 Wm PR-gathers become near-sequential (ascending stencil) -> each
//    XCD reads only its PR slice;
//  * it2's u-pull from the 9 Wm planes becomes windowed (row i pulls
//    kp≈rank(i)±128) -> per-XCD slices, kills ~21MB/iter of duplication.
// k_it2 is UNCHANGED (gU encodes permuted indices). CM graph is truly
// random (not localizable); Wc left unpermuted (6/15 of u_all, dirB
// wouldn't localize). S2 permuted copy lives in LOC_flows rows 36..71.
// ws +0.74MB = ~41.5MB (< proven 43.4).
// ---------------------------------------------------------------------------

#define TPB 256

__device__ __forceinline__ float blockReduce256(float v) {
  #pragma unroll
  for (int o = 32; o > 0; o >>= 1) v += __shfl_down(v, o, 64);
  __shared__ float s[4];
  int lane = threadIdx.x & 63, wv = threadIdx.x >> 6;
  if (lane == 0) s[wv] = v;
  __syncthreads();
  return (threadIdx.x == 0) ? (s[0] + s[1] + s[2] + s[3]) : 0.f;
}

// vectors, diag, b, scal, CNT zero, sCNT zero, b.b  (grid: 3*Bn)
__global__ void k_init0(const float* __restrict__ KUw, const float* __restrict__ kToUconf,
                        const float* __restrict__ lmbda, const float* __restrict__ known,
                        const float* __restrict__ kToU,
                        float* __restrict__ diag_ku, float2* __restrict__ PR,
                        float* __restrict__ x,
                        int* __restrict__ CNT, int* __restrict__ sCNT,
                        float* __restrict__ scal, int N)
{
  int i = blockIdx.x * TPB + threadIdx.x;
  if (i < 80) scal[i] = 0.f;
  if (i < 576) sCNT[i] = 0;
  if (i < 3 * N) CNT[i] = 0;
  float red = 0.f;
  if (i < N) {
    float dk = KUw[i] * kToUconf[i] + lmbda[0] * known[i];
    diag_ku[i] = dk;
    float b = dk * kToU[i];
    PR[i] = make_float2(b, b);   // (p_old, r); first iter beta=0 -> p = r = b
    x[i] = 0.f;
    red = b * b;
  }
  float v = blockReduce256(red);
  if (threadIdx.x == 0) atomicAdd(&scal[0], v);
}

// in-place symmetrization: LOC_flows rows 0..35 <- 0.5*w*(F_ab+F_ba), a<b.
// Thread k owns column k; harness restores d_in before every launch.
__global__ void k_prep(float* __restrict__ LOC_flows, const int* __restrict__ LOC_inInd,
                       const float* __restrict__ LOCw, int NLOC)
{
  int k = blockIdx.x * TPB + threadIdx.x;
  float Fl[81];
  #pragma unroll
  for (int m = 0; m < 81; ++m) Fl[m] = LOC_flows[(size_t)m * NLOC + k];
  float hw = 0.5f * LOCw[LOC_inInd[k]];
  int idx = 0;
  #pragma unroll
  for (int a = 0; a < 9; ++a)
    #pragma unroll
    for (int b = a + 1; b < 9; ++b) {
      LOC_flows[(size_t)idx * NLOC + k] = hw * (Fl[a * 9 + b] + Fl[b * 9 + a]);
      ++idx;
    }
}

// bucket-sort pass 1: count + ticket  (grid: Bl)
__global__ void k_sh(const int* __restrict__ LOC_inInd, int* __restrict__ sCNT,
                     unsigned short* __restrict__ sTick, int NLOC)
{
  int k = blockIdx.x * TPB + threadIdx.x;
  sTick[k] = (unsigned short)atomicAdd(&sCNT[LOC_inInd[k] >> 8], 1);
}

// bucket-sort pass 2: exclusive scan of 576 counters (1 block x 576)
__global__ void k_ss(int* __restrict__ sCNT)
{
  __shared__ int s[576];
  int v = sCNT[threadIdx.x];
  s[threadIdx.x] = v;
  __syncthreads();
  for (int o = 1; o < 576; o <<= 1) {
    int t = (threadIdx.x >= o) ? s[threadIdx.x - o] : 0;
    __syncthreads();
    s[threadIdx.x] += t;
    __syncthreads();
  }
  sCNT[threadIdx.x] = s[threadIdx.x] - v;
}

// bucket-sort pass 3: scatter perm + permuted LOC_inInd  (grid: Bl)
__global__ void k_sc(const int* __restrict__ LOC_inInd, const int* __restrict__ sCNT,
                     const unsigned short* __restrict__ sTick,
                     int* __restrict__ perm, int* __restrict__ LOC_inIndP, int NLOC)
{
  int k = blockIdx.x * TPB + threadIdx.x;
  int v = LOC_inInd[k];
  int pos = sCNT[v >> 8] + sTick[k];
  perm[pos] = k;
  LOC_inIndP[pos] = v;
}

// permuted copy of symmetrized S2: rows 36..71 col kp <- rows 0..35 col perm[kp]
__global__ void k_permS2(float* __restrict__ LOC_flows, const int* __restrict__ perm,
                         int NLOC)
{
  int kp = blockIdx.x * TPB + threadIdx.x;
  int k = perm[kp];
  #pragma unroll
  for (int m = 0; m < 36; ++m)
    LOC_flows[(size_t)(36 + m) * NLOC + kp] = LOC_flows[(size_t)m * NLOC + k];
}

// histograms + tickets  (grid: Bz + Bl + Bl)  — Wm branch uses permuted kp
__global__ void k_hist(const int* __restrict__ Wrow, const int* __restrict__ Wcol,
                       const int* __restrict__ LOC_inIndP, const int* __restrict__ width_p,
                       const int* __restrict__ IU_inInd, const int* __restrict__ IU_neighInd,
                       int* __restrict__ CNT,
                       unsigned short* __restrict__ tr, unsigned short* __restrict__ tc,
                       unsigned short* __restrict__ tU,
                       int NLOC, int N, int B0, int B1)
{
  int blk = blockIdx.x;
  if (blk < B0) {
    int e = blk * TPB + threadIdx.x;
    tr[e] = (unsigned short)atomicAdd(&CNT[Wrow[e]], 1);
    tc[e] = (unsigned short)atomicAdd(&CNT[N + Wcol[e]], 1);
  } else if (blk < B1) {                // Wm: (kp,a) by out-row, permuted order
    int kp = (blk - B0) * TPB + threadIdx.x;
    int wd = *width_p;
    int base = LOC_inIndP[kp];
    const int offs[9] = {-1 - wd, -1, -1 + wd, -wd, 0, wd, 1 - wd, 1, 1 + wd};
    #pragma unroll
    for (int a = 0; a < 9; ++a)
      tU[a * NLOC + kp] = (unsigned short)atomicAdd(&CNT[2 * N + base + offs[a]], 1);
  } else {                              // Wc: dirA k by r0, dirB (k,j) by c0
    int k = (blk - B1) * TPB + threadIdx.x;
    tU[14 * NLOC + k] = (unsigned short)atomicAdd(&CNT[2 * N + IU_inInd[k]], 1);
    #pragma unroll
    for (int j = 0; j < 5; ++j)
      tU[(9 + j) * NLOC + k] =
          (unsigned short)atomicAdd(&CNT[2 * N + IU_neighInd[k * 5 + j]], 1);
  }
}

// in-place exclusive scan (OFF==CNT)
__global__ void k_scan1(int* __restrict__ OFF, int* __restrict__ bsum, int tot)
{
  __shared__ int s[TPB];
  int gid = blockIdx.x * TPB + threadIdx.x;
  int v = (gid < tot) ? OFF[gid] : 0;
  s[threadIdx.x] = v;
  __syncthreads();
  #pragma unroll
  for (int o = 1; o < TPB; o <<= 1) {
    int t = (threadIdx.x >= o) ? s[threadIdx.x - o] : 0;
    __syncthreads();
    s[threadIdx.x] += t;
    __syncthreads();
  }
  if (gid < tot) OFF[gid] = s[threadIdx.x] - v;
  if (threadIdx.x == TPB - 1) bsum[blockIdx.x] = s[threadIdx.x];
}

__global__ void k_scan2(int* __restrict__ bsum, int nPerArr)  // 3 blocks x 1024
{
  __shared__ int s[1024];
  int base = blockIdx.x * nPerArr;
  int v = (threadIdx.x < nPerArr) ? bsum[base + threadIdx.x] : 0;
  s[threadIdx.x] = v;
  __syncthreads();
  for (int o = 1; o < 1024; o <<= 1) {
    int t = (threadIdx.x >= o) ? s[threadIdx.x - o] : 0;
    __syncthreads();
    s[threadIdx.x] += t;
    __syncthreads();
  }
  if (threadIdx.x < nPerArr) bsum[base + threadIdx.x] = s[threadIdx.x] - v;
}

__global__ void k_scan3(int* __restrict__ OFF, const int* __restrict__ bsum, int tot)
{
  int gid = blockIdx.x * TPB + threadIdx.x;
  if (gid < tot) OFF[gid] += bsum[blockIdx.x];
}

// atomic-free fill: pos = OFF[key] + ticket  (grid: Bz + Bl + Bl)
__global__ void k_fill(const float* __restrict__ CMw, const float* __restrict__ Wcm_data,
                       const int* __restrict__ Wrow, const int* __restrict__ Wcol,
                       const int* __restrict__ LOC_inIndP, const int* __restrict__ width_p,
                       const int* __restrict__ IU_inInd, const int* __restrict__ IU_neighInd,
                       const int* __restrict__ OFF,
                       const unsigned short* __restrict__ tr, const unsigned short* __restrict__ tc,
                       const unsigned short* __restrict__ tU,
                       int2* __restrict__ csrPk, int2* __restrict__ cscPk,
                       int* __restrict__ gU,
                       int NLOC, int N, int B0, int B1)
{
  int blk = blockIdx.x;
  if (blk < B0) {
    int e = blk * TPB + threadIdx.x;
    int row = Wrow[e], col = Wcol[e];
    int cv = __float_as_int(CMw[row] * Wcm_data[e]);
    csrPk[OFF[row] + tr[e]] = make_int2(col, cv);
    cscPk[OFF[N + col] + tc[e]] = make_int2(row, cv);
  } else if (blk < B1) {                // Wm permuted
    int kp = (blk - B0) * TPB + threadIdx.x;
    int wd = *width_p;
    int base = LOC_inIndP[kp];
    const int offs[9] = {-1 - wd, -1, -1 + wd, -wd, 0, wd, 1 - wd, 1, 1 + wd};
    #pragma unroll
    for (int a = 0; a < 9; ++a)
      gU[OFF[2 * N + base + offs[a]] + tU[a * NLOC + kp]] = a * NLOC + kp;
  } else {
    int k = (blk - B1) * TPB + threadIdx.x;
    gU[OFF[2 * N + IU_inInd[k]] + tU[14 * NLOC + k]] = 14 * NLOC + k;
    #pragma unroll
    for (int j = 0; j < 5; ++j)
      gU[OFF[2 * N + IU_neighInd[k * 5 + j]] + tU[(9 + j) * NLOC + k]] =
          (9 + j) * NLOC + k;
  }
}

// pass 1: p = fma(beta, p_old, r) on the fly; Wm (permuted, near-sequential
// PR gathers) / Wc -> u_all; CSR Lv/rs_cm (8-wide); pAp.  grid: Bl + Bl + Bn
__global__ void k_it1(const float2* __restrict__ PR,
                      const float* __restrict__ S2p, const int* __restrict__ LOC_inIndP,
                      const int* __restrict__ width_p,
                      const float* __restrict__ IU_flows, const int* __restrict__ IU_inInd,
                      const int* __restrict__ IU_neighInd, const float* __restrict__ IUw,
                      const float* __restrict__ diag_ku,
                      const int* __restrict__ OFF, const int2* __restrict__ csrPk,
                      float* __restrict__ u_all,
                      float* __restrict__ Lv, float* __restrict__ rs_cm,
                      const float* __restrict__ rsN, const float* __restrict__ rsO, int first,
                      float* __restrict__ pAp_t,
                      int NNZ, int NLOC, int N, int B0, int B1)
{
  int blk = blockIdx.x;
  float beta = first ? 0.f : rsN[0] / rsO[0];
  float red = 0.f;
  if (blk < B0) {                       // Wm via symmetric pair coefficients
    int kp = blk * TPB + threadIdx.x;
    int wd = *width_p;
    int base = LOC_inIndP[kp];
    const int offs[9] = {-1 - wd, -1, -1 + wd, -wd, 0, wd, 1 - wd, 1, 1 + wd};
    float pv[9];
    #pragma unroll
    for (int a = 0; a < 9; ++a) {
      float2 pr = PR[base + offs[a]];
      pv[a] = __builtin_fmaf(beta, pr.x, pr.y);
    }
    float u[9] = {0.f, 0.f, 0.f, 0.f, 0.f, 0.f, 0.f, 0.f, 0.f};
    float qf = 0.f;
    int idx = 0;
    #pragma unroll
    for (int a = 0; a < 9; ++a)
      #pragma unroll
      for (int b = a + 1; b < 9; ++b) {
        float sv = S2p[(size_t)idx * NLOC + kp];
        ++idx;
        float d = pv[a] - pv[b];
        float t = sv * d;
        u[a] += t; u[b] -= t;
        qf += t * d;
      }
    #pragma unroll
    for (int a = 0; a < 9; ++a) u_all[a * NLOC + kp] = u[a];
    red = qf;
  } else if (blk < B1) {                // Wc
    int k = (blk - B0) * TPB + threadIdx.x;
    int r0 = IU_inInd[k];
    float hw = 0.5f * IUw[r0];
    float2 prr = PR[r0];
    float pr = __builtin_fmaf(beta, prr.x, prr.y);
    int c[5]; float w[5];
    #pragma unroll
    for (int j = 0; j < 5; ++j) {
      c[j] = IU_neighInd[k * 5 + j];
      w[j] = hw * IU_flows[k * 5 + j];
    }
    float pc[5];
    #pragma unroll
    for (int j = 0; j < 5; ++j) {
      float2 pp = PR[c[j]];
      pc[j] = __builtin_fmaf(beta, pp.x, pp.y);
    }
    float qf = 0.f, asum = 0.f;
    #pragma unroll
    for (int j = 0; j < 5; ++j) {
      float d = pr - pc[j];
      float uA = w[j] * d;
      u_all[(9 + j) * NLOC + k] = -uA;   // direction B (row c0)
      asum += uA;
      qf += uA * d;
    }
    u_all[14 * NLOC + k] = asum;          // direction A row-sum (row r0)
    red = qf;
  } else {                              // CSR: Lv = sum cv (p_i - p_c), 8-wide
    int i = (blk - B1) * TPB + threadIdx.x;
    float2 pri = PR[i];
    float pi = __builtin_fmaf(beta, pri.x, pri.y);
    int s = OFF[i];
    int e = (i == N - 1) ? NNZ : OFF[i + 1];
    float acc = 0.f, rs = 0.f;
    int q = s;
    for (; q + 8 <= e; q += 8) {
      int2 ed[8];
      #pragma unroll
      for (int m = 0; m < 8; ++m) ed[m] = csrPk[q + m];
      float g[8];
      #pragma unroll
      for (int m = 0; m < 8; ++m) {
        float2 pp = PR[ed[m].x];
        g[m] = __builtin_fmaf(beta, pp.x, pp.y);
      }
      #pragma unroll
      for (int m = 0; m < 8; ++m) {
        float cv = __int_as_float(ed[m].y);
        rs += cv;
        acc += cv * (pi - g[m]);
      }
    }
    for (; q + 4 <= e; q += 4) {
      int2 ed[4];
      #pragma unroll
      for (int m = 0; m < 4; ++m) ed[m] = csrPk[q + m];
      float g[4];
      #pragma unroll
      for (int m = 0; m < 4; ++m) {
        float2 pp = PR[ed[m].x];
        g[m] = __builtin_fmaf(beta, pp.x, pp.y);
      }
      #pragma unroll
      for (int m = 0; m < 4; ++m) {
        float cv = __int_as_float(ed[m].y);
        rs += cv;
        acc += cv * (pi - g[m]);
      }
    }
    for (; q < e; ++q) {
      int2 ed = csrPk[q];
      float cv = __int_as_float(ed.y);
      float2 pp = PR[ed.x];
      rs += cv;
      acc += cv * (pi - __builtin_fmaf(beta, pp.x, pp.y));
    }
    Lv[i] = acc;
    rs_cm[i] = rs;
    red = diag_ku[i] * pi * pi + acc * acc;
  }
  float v = blockReduce256(red);
  if (threadIdx.x == 0) atomicAdd(pAp_t, v);
}

// pass 2: Ap = diag p + rs_cm Lv - csc_pull(Lv) + u-pull; x += alpha p;
// PR <- (p, r_new); r.r   (grid: Bn; unchanged from R14)
__global__ void k_it2(float* __restrict__ x, float2* __restrict__ PR,
                      const float* __restrict__ Lv,
                      const float* __restrict__ rs_cm, const float* __restrict__ diag_ku,
                      const int* __restrict__ OFF,
                      const int2* __restrict__ cscPk,
                      const int* __restrict__ gU, const float* __restrict__ u_all,
                      const float* __restrict__ rs_t, const float* __restrict__ pAp_t,
                      const float* __restrict__ rsO, int first,
                      float* __restrict__ rs_t1,
                      int NNZ, int NLOC, int N)
{
  int i = blockIdx.x * TPB + threadIdx.x;
  float alpha = rs_t[0] / pAp_t[0];
  float beta = first ? 0.f : rs_t[0] / rsO[0];
  // unified u-pull (Wm + WcA + WcB), 8/4/1-wide
  float tg = 0.f;
  {
    int s0 = OFF[2 * N + i];
    int e0 = (i == N - 1) ? 15 * NLOC : OFF[2 * N + i + 1];
    int q = s0;
    for (; q + 8 <= e0; q += 8) {
      int g[8];
      #pragma unroll
      for (int m = 0; m < 8; ++m) g[m] = gU[q + m];
      float u[8];
      #pragma unroll
      for (int m = 0; m < 8; ++m) u[m] = u_all[g[m]];
      #pragma unroll
      for (int m = 0; m < 8; ++m) tg += u[m];
    }
    for (; q + 4 <= e0; q += 4) {
      int g[4];
      #pragma unroll
      for (int m = 0; m < 4; ++m) g[m] = gU[q + m];
      float u[4];
      #pragma unroll
      for (int m = 0; m < 4; ++m) u[m] = u_all[g[m]];
      #pragma unroll
      for (int m = 0; m < 4; ++m) tg += u[m];
    }
    for (; q < e0; ++q) tg += u_all[gU[q]];
  }
  // CM: W^T Lv via CSC, 8/4/1-wide
  float sc = 0.f;
  {
    int s0 = OFF[N + i];
    int e0 = (i == N - 1) ? NNZ : OFF[N + i + 1];
    int q = s0;
    for (; q + 8 <= e0; q += 8) {
      int2 ed[8];
      #pragma unroll
      for (int m = 0; m < 8; ++m) ed[m] = cscPk[q + m];
      float l[8];
      #pragma unroll
      for (int m = 0; m < 8; ++m) l[m] = Lv[ed[m].x];
      #pragma unroll
      for (int m = 0; m < 8; ++m) sc += __int_as_float(ed[m].y) * l[m];
    }
    for (; q + 4 <= e0; q += 4) {
      int2 ed[4];
      #pragma unroll
      for (int m = 0; m < 4; ++m) ed[m] = cscPk[q + m];
      float l[4];
      #pragma unroll
      for (int m = 0; m < 4; ++m) l[m] = Lv[ed[m].x];
      #pragma unroll
      for (int m = 0; m < 4; ++m) sc += __int_as_float(ed[m].y) * l[m];
    }
    for (; q < e0; ++q) {
      int2 ed = cscPk[q];
      sc += __int_as_float(ed.y) * Lv[ed.x];
    }
  }
  float2 pri = PR[i];
  float pi = __builtin_fmaf(beta, pri.x, pri.y);
  float Ap = diag_ku[i] * pi + rs_cm[i] * Lv[i] - sc + tg;
  x[i] += alpha * pi;
  float rn = pri.y - alpha * Ap;
  PR[i] = make_float2(pi, rn);          // (p_old, r) for next iteration
  float v = blockReduce256(rn * rn);
  if (threadIdx.x == 0) atomicAdd(rs_t1, v);
}

extern "C" void kernel_launch(void* const* d_in, const int* in_sizes, int n_in,
                              void* d_out, int out_size, void* d_ws, size_t ws_size,
                              hipStream_t stream)
{
  const float* CMw       = (const float*)d_in[0];
  const float* LOCw      = (const float*)d_in[1];
  const float* IUw       = (const float*)d_in[2];
  const float* KUw       = (const float*)d_in[3];
  const float* lmbda     = (const float*)d_in[4];
  const float* kToUconf  = (const float*)d_in[5];
  const float* known     = (const float*)d_in[6];
  const float* kToU      = (const float*)d_in[7];
  const float* Wcm_data  = (const float*)d_in[8];
  float*       LOC_flows = (float*)d_in[9];      // overwritten in-place by k_prep
                                                 // + permuted S2 copy in rows 36..71;
                                                 // harness restores d_in every launch
  const float* IU_flows  = (const float*)d_in[10];
  const int*   Wrow      = (const int*)d_in[11];
  const int*   Wcol      = (const int*)d_in[12];
  const int*   LOC_inInd = (const int*)d_in[13];
  const int*   IU_inInd  = (const int*)d_in[14];
  const int*   IU_neighInd = (const int*)d_in[15];
  const int*   width_p   = (const int*)d_in[16];
  const int CG_STEPS = 30;

  const int N    = in_sizes[0];      // 147456 (% 256 == 0)
  const int NNZ  = in_sizes[8];      // 1474560
  const int NLOC = in_sizes[13];     // 73728

  // ---- workspace layout, ~41.5 MB ----
  float* x       = (float*)d_out;
  float2* PR     = (float2*)d_ws;                // N float2 (p_old, r)
  float* Lv      = (float*)(PR + (size_t)N);     // N
  float* rs_cm   = Lv + N;                       // N
  float* diag_ku = rs_cm + N;                    // N
  int2*  csrPk   = (int2*)(diag_ku + N);         // NNZ int2
  int2*  cscPk   = csrPk + (size_t)NNZ;          // NNZ int2
  int*   gU      = (int*)(cscPk + (size_t)NNZ);  // 15*NLOC
  int*   OFF     = gU + (size_t)15 * NLOC;       // 3N (in-place CNT -> OFF)
  unsigned short* tr = (unsigned short*)(OFF + (size_t)3 * N);  // NNZ u16
  unsigned short* tc = tr + (size_t)NNZ;         // NNZ u16
  unsigned short* tU = tc + (size_t)NNZ;         // 15*NLOC u16
  float* u_all   = (float*)tr;                   // 15*NLOC floats, aliases tickets
                                                 // (tickets dead after k_fill)
  int*   bsum    = (int*)(tU + (size_t)15 * NLOC);  // 3*(N/256)
  float* scal    = (float*)(bsum + 3 * (N / TPB));  // 80 floats
  // --- sort scratch (new in R15) ---
  int*   perm    = (int*)(scal + 80);            // NLOC
  int*   LOC_inIndP = perm + NLOC;               // NLOC
  int*   sCNT    = LOC_inIndP + NLOC;            // 576
  unsigned short* sTick = (unsigned short*)(sCNT + 576); // NLOC u16

  const int Bn = N / TPB;        // 576
  const int Bz = NNZ / TPB;      // 5760
  const int Bl = NLOC / TPB;     // 288
  const int Z3 = 3 * Bn;

  k_init0<<<Z3, TPB, 0, stream>>>(KUw, kToUconf, lmbda, known, kToU,
                                  diag_ku, PR, x, OFF, sCNT, scal, N);
  k_prep<<<Bl, TPB, 0, stream>>>(LOC_flows, LOC_inInd, LOCw, NLOC);
  k_sh<<<Bl, TPB, 0, stream>>>(LOC_inInd, sCNT, sTick, NLOC);
  k_ss<<<1, 576, 0, stream>>>(sCNT);
  k_sc<<<Bl, TPB, 0, stream>>>(LOC_inInd, sCNT, sTick, perm, LOC_inIndP, NLOC);
  k_permS2<<<Bl, TPB, 0, stream>>>(LOC_flows, perm, NLOC);
  k_hist<<<Bz + 2 * Bl, TPB, 0, stream>>>(Wrow, Wcol, LOC_inIndP, width_p,
                                          IU_inInd, IU_neighInd, OFF,
                                          tr, tc, tU, NLOC, N, Bz, Bz + Bl);
  k_scan1<<<Z3, TPB, 0, stream>>>(OFF, bsum, 3 * N);
  k_scan2<<<3, 1024, 0, stream>>>(bsum, Bn);
  k_scan3<<<Z3, TPB, 0, stream>>>(OFF, bsum, 3 * N);
  k_fill<<<Bz + 2 * Bl, TPB, 0, stream>>>(CMw, Wcm_data, Wrow, Wcol,
                                          LOC_inIndP, width_p, IU_inInd, IU_neighInd,
                                          OFF, tr, tc, tU,
                                          csrPk, cscPk, gU,
                                          NLOC, N, Bz, Bz + Bl);

  const float* S2p = LOC_flows + (size_t)36 * NLOC;
  for (int t = 0; t < CG_STEPS; ++t) {
    const float* rsN = scal + t;
    const float* rsO = scal + (t == 0 ? 0 : t - 1);
    k_it1<<<2 * Bl + Bn, TPB, 0, stream>>>(
        PR, S2p, LOC_inIndP, width_p,
        IU_flows, IU_inInd, IU_neighInd, IUw,
        diag_ku, OFF, csrPk, u_all, Lv, rs_cm,
        rsN, rsO, (t == 0) ? 1 : 0, scal + 40 + t,
        NNZ, NLOC, N, Bl, 2 * Bl);
    k_it2<<<Bn, TPB, 0, stream>>>(
        x, PR, Lv, rs_cm, diag_ku, OFF, cscPk, gU, u_all,
        rsN, scal + 40 + t, rsO, (t == 0) ? 1 : 0, scal + t + 1,
        NNZ, NLOC, N);
  }
}